// Round 1
// baseline (840.228 us; speedup 1.0000x reference)
//
#include <hip/hip_runtime.h>
#include <math.h>

// Problem constants (match reference)
#define NN   2048
#define NE   16384
#define NET  (NE + NN)   // 18432 edges incl. self loops
#define INF_ 128
#define OUTF 128
#define NH   4
#define OHF  8
#define NEG_SLOPE 0.2f
#define CAP  512         // max in-degree supported (actual max ~25 for this seed)

__device__ __forceinline__ float symlogf_(float v) {
    float s = log1pf(fabsf(v));
    return v < 0.0f ? -s : s;
}

// ---------------------------------------------------------------------------
// K1: per-row bitonic sort (LDS) + symlog + conv1(1->8,k3,p1)+relu +
//     conv2(8->16,k3,p1)+relu + mean-pool + fc(16->8).
//     Also writes slog = symlog(onehot) (unsorted) for the dot-attention.
// ---------------------------------------------------------------------------
__global__ __launch_bounds__(256) void k_sortconv(
    const float* __restrict__ onehot,
    const float* __restrict__ c1w, const float* __restrict__ c1b,
    const float* __restrict__ c2w, const float* __restrict__ c2b,
    const float* __restrict__ fcw, const float* __restrict__ fcb,
    float* __restrict__ slog, float* __restrict__ ohfeat) {
    __shared__ float vals[NN];
    __shared__ float w1s[24], b1s[8], w2s[384], b2s[16], fcws[128], fcbs[8];
    __shared__ float red[64];
    __shared__ float pooled[16];
    const int tid = threadIdx.x;
    const int r   = blockIdx.x;
    const float* row  = onehot + (size_t)r * NN;
    float*       srow = slog   + (size_t)r * NN;
    for (int i = tid; i < NN; i += 256) {
        float v = row[i];
        vals[i] = v;
        srow[i] = symlogf_(v);
    }
    for (int i = tid; i < 24;  i += 256) w1s[i] = c1w[i];
    for (int i = tid; i < 8;   i += 256) { b1s[i] = c1b[i]; fcbs[i] = fcb[i]; }
    for (int i = tid; i < 384; i += 256) w2s[i] = c2w[i];
    for (int i = tid; i < 16;  i += 256) b2s[i] = c2b[i];
    for (int i = tid; i < 128; i += 256) fcws[i] = fcw[i];

    // Bitonic sort, ascending (jnp.sort)
    for (int k = 2; k <= NN; k <<= 1) {
        for (int j = k >> 1; j > 0; j >>= 1) {
            __syncthreads();
            for (int i = tid; i < NN; i += 256) {
                int ixj = i ^ j;
                if (ixj > i) {
                    float a = vals[i], b = vals[ixj];
                    bool up = ((i & k) == 0);
                    if ((a > b) == up) { vals[i] = b; vals[ixj] = a; }
                }
            }
        }
    }
    __syncthreads();
    for (int i = tid; i < NN; i += 256) vals[i] = symlogf_(vals[i]);
    __syncthreads();

    // Fused conv pipeline; each thread owns 8 contiguous output positions.
    float colA[8], colB[8], colC[8], sums[16];
    for (int c = 0; c < 16; c++) sums[c] = 0.0f;
    const int base = tid * 8;
    auto h1col = [&](int p, float* col) {
        if (p < 0 || p >= NN) { for (int c = 0; c < 8; c++) col[c] = 0.0f; return; }
        float pm = (p > 0)      ? vals[p - 1] : 0.0f;
        float pc = vals[p];
        float pp = (p < NN - 1) ? vals[p + 1] : 0.0f;
        for (int c = 0; c < 8; c++) {
            float a = b1s[c] + w1s[c*3]*pm + w1s[c*3+1]*pc + w1s[c*3+2]*pp;
            col[c] = fmaxf(a, 0.0f);
        }
    };
    h1col(base - 1, colA);
    h1col(base,     colB);
    for (int i = 0; i < 8; i++) {
        h1col(base + i + 1, colC);
        for (int ch = 0; ch < 16; ch++) {
            float a = b2s[ch];
            const float* w = &w2s[ch * 24];
            for (int c = 0; c < 8; c++)
                a += w[c*3]*colA[c] + w[c*3+1]*colB[c] + w[c*3+2]*colC[c];
            sums[ch] += fmaxf(a, 0.0f);
        }
        for (int c = 0; c < 8; c++) { colA[c] = colB[c]; colB[c] = colC[c]; }
    }
    // Block reduction of per-thread channel sums.
    const int wave = tid >> 6, lane = tid & 63;
    for (int c = 0; c < 16; c++)
        for (int o = 32; o; o >>= 1) sums[c] += __shfl_down(sums[c], o);
    if (lane == 0)
        for (int c = 0; c < 16; c++) red[wave*16 + c] = sums[c];
    __syncthreads();
    if (tid < 16)
        pooled[tid] = (red[tid] + red[16+tid] + red[32+tid] + red[48+tid]) * (1.0f / NN);
    __syncthreads();
    if (tid < OHF) {
        float a = fcbs[tid];
        for (int c = 0; c < 16; c++) a += fcws[tid*16 + c] * pooled[c];
        ohfeat[r*OHF + tid] = a;
    }
}

// ---------------------------------------------------------------------------
// K2: xh = concat([x, oh_feat]) @ lin_w.T   -> [N, 512]
//     4 nodes per block so lin_w L2 traffic is amortized 4x.
// ---------------------------------------------------------------------------
__global__ __launch_bounds__(256) void k_xh(
    const float* __restrict__ x, const float* __restrict__ ohf,
    const float* __restrict__ lin_w, float* __restrict__ xh) {
    const int n0 = blockIdx.x * 4;
    __shared__ float xin[4][136];
    const int tid = threadIdx.x;
    for (int i = tid; i < 4 * 136; i += 256) {
        int nn = i / 136, k = i - nn * 136;
        xin[nn][k] = (k < INF_) ? x[(size_t)(n0+nn)*INF_ + k]
                                : ohf[(n0+nn)*OHF + (k - INF_)];
    }
    __syncthreads();
    for (int o = tid; o < 512; o += 256) {
        const float4* wr4 = (const float4*)(lin_w + (size_t)o * 136);
        float a0 = 0, a1 = 0, a2 = 0, a3 = 0;
        for (int kk = 0; kk < 34; kk++) {
            float4 w = wr4[kk];
            int k = kk * 4;
            a0 += w.x*xin[0][k] + w.y*xin[0][k+1] + w.z*xin[0][k+2] + w.w*xin[0][k+3];
            a1 += w.x*xin[1][k] + w.y*xin[1][k+1] + w.z*xin[1][k+2] + w.w*xin[1][k+3];
            a2 += w.x*xin[2][k] + w.y*xin[2][k+1] + w.z*xin[2][k+2] + w.w*xin[2][k+3];
            a3 += w.x*xin[3][k] + w.y*xin[3][k+1] + w.z*xin[3][k+2] + w.w*xin[3][k+3];
        }
        xh[(size_t)(n0+0)*512 + o] = a0;
        xh[(size_t)(n0+1)*512 + o] = a1;
        xh[(size_t)(n0+2)*512 + o] = a2;
        xh[(size_t)(n0+3)*512 + o] = a3;
    }
}

// ---------------------------------------------------------------------------
// K3: sa/ra attention logits per (node, head). 4 waves/block, 1 node/block.
// ---------------------------------------------------------------------------
__global__ __launch_bounds__(256) void k_attn(
    const float* __restrict__ xh, const float* __restrict__ att_l,
    const float* __restrict__ att_r, float* __restrict__ sa,
    float* __restrict__ ra) {
    const int n = blockIdx.x;
    const int tid = threadIdx.x, wave = tid >> 6, lane = tid & 63;
    const float* xr = xh + (size_t)n * 512 + wave * 128;
    float v0 = xr[lane], v1 = xr[lane + 64];
    float pl = v0 * att_l[wave*128 + lane] + v1 * att_l[wave*128 + lane + 64];
    float pr = v0 * att_r[wave*128 + lane] + v1 * att_r[wave*128 + lane + 64];
    for (int o = 32; o; o >>= 1) { pl += __shfl_down(pl, o); pr += __shfl_down(pr, o); }
    if (lane == 0) { sa[n*4 + wave] = pl; ra[n*4 + wave] = pr; }
}

// ---------------------------------------------------------------------------
// CSR build by destination (counting sort).
// ---------------------------------------------------------------------------
__global__ void k_count(const int* __restrict__ dst, int* __restrict__ deg) {
    int e = blockIdx.x * 256 + threadIdx.x;
    if (e < NET) {
        int d = (e < NE) ? dst[e] : (e - NE);
        atomicAdd(&deg[d], 1);
    }
}

__global__ __launch_bounds__(256) void k_scan(
    const int* __restrict__ deg, int* __restrict__ csr_off,
    int* __restrict__ csr_pos) {
    __shared__ int tot[256];
    __shared__ int base[257];
    const int t = threadIdx.x;
    int loc[8], s = 0;
    for (int k = 0; k < 8; k++) { loc[k] = deg[t*8 + k]; s += loc[k]; }
    tot[t] = s;
    __syncthreads();
    if (t == 0) {
        int acc = 0;
        for (int i = 0; i < 256; i++) { base[i] = acc; acc += tot[i]; }
        base[256] = acc;
    }
    __syncthreads();
    int b = base[t];
    for (int k = 0; k < 8; k++) {
        csr_off[t*8 + k] = b;
        csr_pos[t*8 + k] = b;
        b += loc[k];
    }
    if (t == 0) csr_off[NN] = base[256];
}

__global__ void k_fill(const int* __restrict__ dst, int* __restrict__ csr_pos,
                       int* __restrict__ csr_e) {
    int e = blockIdx.x * 256 + threadIdx.x;
    if (e < NET) {
        int d = (e < NE) ? dst[e] : (e - NE);
        int pos = atomicAdd(&csr_pos[d], 1);
        csr_e[pos] = e;
    }
}

// ---------------------------------------------------------------------------
// K4: per-edge raw attention: leaky_relu(sa[s]+ra[d]) / (slog[s].slog[d] + 1)
// ---------------------------------------------------------------------------
__global__ __launch_bounds__(256) void k_alpha(
    const int* __restrict__ src, const int* __restrict__ dst,
    const float* __restrict__ slog, const float* __restrict__ sa,
    const float* __restrict__ ra, float* __restrict__ alpha) {
    const int e = blockIdx.x;
    int s, d;
    if (e < NE) { s = src[e]; d = dst[e]; } else { s = d = e - NE; }
    const int tid = threadIdx.x;
    const float4* A = (const float4*)(slog + (size_t)s * NN);
    const float4* B = (const float4*)(slog + (size_t)d * NN);
    float4 a0 = A[tid*2], a1 = A[tid*2 + 1];
    float4 b0 = B[tid*2], b1 = B[tid*2 + 1];
    float p = a0.x*b0.x + a0.y*b0.y + a0.z*b0.z + a0.w*b0.w
            + a1.x*b1.x + a1.y*b1.y + a1.z*b1.z + a1.w*b1.w;
    for (int o = 32; o; o >>= 1) p += __shfl_down(p, o);
    __shared__ float ps[4];
    const int wave = tid >> 6, lane = tid & 63;
    if (lane == 0) ps[wave] = p;
    __syncthreads();
    if (tid == 0) {
        float dot  = ps[0] + ps[1] + ps[2] + ps[3];
        float datt = 1.0f / (dot + 1.0f);
        float4 out;
        float* po = (float*)&out;
        for (int h = 0; h < 4; h++) {
            float a = sa[s*4 + h] + ra[d*4 + h];
            a = (a >= 0.0f) ? a : NEG_SLOPE * a;
            po[h] = a * datt;
        }
        *(float4*)(alpha + (size_t)e * 4) = out;
    }
}

// ---------------------------------------------------------------------------
// K5: per destination node: segment softmax over incoming edges + weighted
//     aggregation of xh[s] rows. new_x = agg + bias.
// ---------------------------------------------------------------------------
__global__ __launch_bounds__(256) void k_soft_aggx(
    const int* __restrict__ src, const int* __restrict__ csr_off,
    const int* __restrict__ csr_e, const float* __restrict__ alpha,
    const float* __restrict__ xh, const float* __restrict__ bias,
    float* __restrict__ out_x) {
    const int d = blockIdx.x;
    const int begin = csr_off[d];
    int deg = csr_off[d + 1] - begin;
    if (deg > CAP) deg = CAP;   // unreachable for this input distribution
    __shared__ float wls[CAP * 4];
    __shared__ int   sls[CAP];
    const int tid = threadIdx.x;
    for (int t = tid; t < deg; t += 256) {
        int e = csr_e[begin + t];
        sls[t] = (e < NE) ? src[e] : (e - NE);
        float4 a = *(const float4*)(alpha + (size_t)e * 4);
        wls[t*4 + 0] = a.x; wls[t*4 + 1] = a.y;
        wls[t*4 + 2] = a.z; wls[t*4 + 3] = a.w;
    }
    __syncthreads();
    const int wave = tid >> 6, lane = tid & 63;
    if (wave < 4) {  // wave w owns head w
        float m = -3.4e38f;
        for (int t = lane; t < deg; t += 64) m = fmaxf(m, wls[t*4 + wave]);
        for (int o = 32; o; o >>= 1) m = fmaxf(m, __shfl_down(m, o));
        m = __shfl(m, 0);
        float s = 0.0f;
        for (int t = lane; t < deg; t += 64) {
            float ex = expf(wls[t*4 + wave] - m);
            wls[t*4 + wave] = ex;
            s += ex;
        }
        for (int o = 32; o; o >>= 1) s += __shfl_down(s, o);
        s = __shfl(s, 0);
        float inv = 1.0f / (s + 1e-16f);
        for (int t = lane; t < deg; t += 64) wls[t*4 + wave] *= inv;
    }
    __syncthreads();
    for (int ho = tid; ho < 512; ho += 256) {
        const int h = ho >> 7;
        float acc = 0.0f;
        for (int t = 0; t < deg; t++)
            acc += wls[t*4 + h] * xh[(size_t)sls[t] * 512 + ho];
        out_x[(size_t)d * 512 + ho] = acc + bias[ho];
    }
}

// ---------------------------------------------------------------------------
// K6: new_onehot = onehot + sum over incoming edges of onehot[s].
// ---------------------------------------------------------------------------
__global__ __launch_bounds__(256) void k_aggoh(
    const float* __restrict__ onehot, const int* __restrict__ src,
    const int* __restrict__ csr_off, const int* __restrict__ csr_e,
    float* __restrict__ out_oh) {
    const int d = blockIdx.x;
    const int begin = csr_off[d], end = csr_off[d + 1];
    const int tid = threadIdx.x;
    const float4* own = (const float4*)(onehot + (size_t)d * NN);
    float4 A = own[tid], B = own[tid + 256];
    for (int p = begin; p < end; p++) {
        int e = csr_e[p];
        int s = (e < NE) ? src[e] : (e - NE);
        const float4* r4 = (const float4*)(onehot + (size_t)s * NN);
        float4 u = r4[tid], v = r4[tid + 256];
        A.x += u.x; A.y += u.y; A.z += u.z; A.w += u.w;
        B.x += v.x; B.y += v.y; B.z += v.z; B.w += v.w;
    }
    float4* o4 = (float4*)(out_oh + (size_t)d * NN);
    o4[tid] = A; o4[tid + 256] = B;
}

// ---------------------------------------------------------------------------
extern "C" void kernel_launch(void* const* d_in, const int* in_sizes, int n_in,
                              void* d_out, int out_size, void* d_ws, size_t ws_size,
                              hipStream_t stream) {
    const float* x      = (const float*)d_in[0];
    const float* onehot = (const float*)d_in[1];
    const int*   src    = (const int*)d_in[2];
    const int*   dst    = (const int*)d_in[3];
    const float* lin_w  = (const float*)d_in[4];
    const float* att_l  = (const float*)d_in[5];
    const float* att_r  = (const float*)d_in[6];
    const float* bias   = (const float*)d_in[7];
    const float* c1w    = (const float*)d_in[8];
    const float* c1b    = (const float*)d_in[9];
    const float* c2w    = (const float*)d_in[10];
    const float* c2b    = (const float*)d_in[11];
    const float* fcw    = (const float*)d_in[12];
    const float* fcb    = (const float*)d_in[13];

    float* out_x  = (float*)d_out;                       // [N, 512]
    float* out_oh = out_x + (size_t)NN * (NH * OUTF);    // [N, N]

    // Workspace layout (~21.5 MB)
    float* ws    = (float*)d_ws;
    float* slog  = ws;                           // N*N
    float* xh    = slog + (size_t)NN * NN;       // N*512
    float* ohf   = xh   + (size_t)NN * 512;      // N*8
    float* sa    = ohf  + (size_t)NN * OHF;      // N*4
    float* ra    = sa   + (size_t)NN * NH;       // N*4
    float* alpha = ra   + (size_t)NN * NH;       // NET*4
    int* deg     = (int*)(alpha + (size_t)NET * 4);
    int* csr_off = deg + NN;                     // N+1
    int* csr_pos = csr_off + NN + 1;             // N
    int* csr_e   = csr_pos + NN;                 // NET

    hipMemsetAsync(deg, 0, NN * sizeof(int), stream);
    k_sortconv<<<NN, 256, 0, stream>>>(onehot, c1w, c1b, c2w, c2b, fcw, fcb, slog, ohf);
    k_count<<<(NET + 255) / 256, 256, 0, stream>>>(dst, deg);
    k_scan<<<1, 256, 0, stream>>>(deg, csr_off, csr_pos);
    k_fill<<<(NET + 255) / 256, 256, 0, stream>>>(dst, csr_pos, csr_e);
    k_xh<<<NN / 4, 256, 0, stream>>>(x, ohf, lin_w, xh);
    k_attn<<<NN, 256, 0, stream>>>(xh, att_l, att_r, sa, ra);
    k_alpha<<<NET, 256, 0, stream>>>(src, dst, slog, sa, ra, alpha);
    k_soft_aggx<<<NN, 256, 0, stream>>>(src, csr_off, csr_e, alpha, xh, bias, out_x);
    k_aggoh<<<NN, 256, 0, stream>>>(onehot, src, csr_off, csr_e, out_oh);
}

// Round 3
// 294.446 us; speedup vs baseline: 2.8536x; 2.8536x over previous
//
#include <hip/hip_runtime.h>
#include <math.h>

// Problem constants (match reference)
#define NN   2048
#define NE   16384
#define NET  (NE + NN)   // 18432 edges incl. self loops
#define INF_ 128
#define OUTF 128
#define NH   4
#define OHF  8
#define NEG_SLOPE 0.2f
#define CAP  512         // max in-degree supported (actual max ~25 for this seed)

__device__ __forceinline__ float symlogf_(float v) {
    float s = log1pf(fabsf(v));
    return v < 0.0f ? -s : s;
}

// ---------------------------------------------------------------------------
// K1: per-row sort (hybrid register/shuffle/LDS bitonic) + symlog +
//     conv1(1->8,k3,p1)+relu + conv2(8->16,k3,p1)+relu + mean-pool + fc(16->8).
//     Also writes slog = symlog(onehot) (unsorted) for the dot-attention.
//     Each thread owns 8 contiguous elements of the 2048-row.
// ---------------------------------------------------------------------------
__global__ __launch_bounds__(256, 2) void k_sortconv(
    const float* __restrict__ onehot,
    const float* __restrict__ c1w, const float* __restrict__ c1b,
    const float* __restrict__ c2w, const float* __restrict__ c2b,
    const float* __restrict__ fcw, const float* __restrict__ fcb,
    float* __restrict__ slog, float* __restrict__ ohfeat) {
    __shared__ float vals[NN];        // 8 KB
    __shared__ float red[64];
    __shared__ float pooled[16];
    const int t = threadIdx.x;
    const int r = blockIdx.x;
    const int b = t << 3;             // base element index of this thread
    const float* row  = onehot + (size_t)r * NN;
    float*       srow = slog   + (size_t)r * NN;

    // ---- load 8 elements into registers; write symlog(unsorted) out ----
    float4 lo = ((const float4*)row)[t * 2];
    float4 hi = ((const float4*)row)[t * 2 + 1];
    float v[8] = {lo.x, lo.y, lo.z, lo.w, hi.x, hi.y, hi.z, hi.w};
    {
        float4 s0, s1;
        s0.x = symlogf_(v[0]); s0.y = symlogf_(v[1]);
        s0.z = symlogf_(v[2]); s0.w = symlogf_(v[3]);
        s1.x = symlogf_(v[4]); s1.y = symlogf_(v[5]);
        s1.z = symlogf_(v[6]); s1.w = symlogf_(v[7]);
        ((float4*)srow)[t * 2]     = s0;
        ((float4*)srow)[t * 2 + 1] = s1;
    }

    // compare-exchange: if up, x=min,y=max; else x=max,y=min
    auto cx = [](float& x, float& y, bool up) {
        float mn = fminf(x, y), mx = fmaxf(x, y);
        x = up ? mn : mx;
        y = up ? mx : mn;
    };

    // ---- in-register phases k=2,4,8 (directions from element-index bits) ----
    // k=2: up iff (i&2)==0
    cx(v[0], v[1], true);  cx(v[2], v[3], false);
    cx(v[4], v[5], true);  cx(v[6], v[7], false);
    // k=4: up iff (i&4)==0
    cx(v[0], v[2], true);  cx(v[1], v[3], true);
    cx(v[4], v[6], false); cx(v[5], v[7], false);
    cx(v[0], v[1], true);  cx(v[2], v[3], true);
    cx(v[4], v[5], false); cx(v[6], v[7], false);
    // k=8: up iff (i&8)==0 -> uniform per thread
    {
        const bool u8 = ((t & 1) == 0);
        cx(v[0], v[4], u8); cx(v[1], v[5], u8); cx(v[2], v[6], u8); cx(v[3], v[7], u8);
        cx(v[0], v[2], u8); cx(v[1], v[3], u8); cx(v[4], v[6], u8); cx(v[5], v[7], u8);
        cx(v[0], v[1], u8); cx(v[2], v[3], u8); cx(v[4], v[5], u8); cx(v[6], v[7], u8);
    }

    // ---- phases k=16..2048 ----
    for (int k = 16; k <= NN; k <<= 1) {
        const bool up = ((b & k) == 0);           // uniform per thread
        for (int j = k >> 1; j >= 8; j >>= 1) {
            const int pj = j >> 3;                // partner distance in threads
            const bool keepmin = (((t & pj) == 0) == up);
            if (pj <= 32) {
                // in-wave exchange, no barrier
                #pragma unroll
                for (int e = 0; e < 8; e++) {
                    float p = __shfl_xor(v[e], pj, 64);
                    v[e] = keepmin ? fminf(v[e], p) : fmaxf(v[e], p);
                }
            } else {
                // cross-wave exchange via LDS (only j=512,1024: 3 total)
                __syncthreads();
                #pragma unroll
                for (int e = 0; e < 8; e++) vals[b + e] = v[e];
                __syncthreads();
                const int pb = (t ^ pj) << 3;
                #pragma unroll
                for (int e = 0; e < 8; e++) {
                    float p = vals[pb + e];
                    v[e] = keepmin ? fminf(v[e], p) : fmaxf(v[e], p);
                }
            }
        }
        // j = 4,2,1 in registers (direction uniform per thread)
        cx(v[0], v[4], up); cx(v[1], v[5], up); cx(v[2], v[6], up); cx(v[3], v[7], up);
        cx(v[0], v[2], up); cx(v[1], v[3], up); cx(v[4], v[6], up); cx(v[5], v[7], up);
        cx(v[0], v[1], up); cx(v[2], v[3], up); cx(v[4], v[5], up); cx(v[6], v[7], up);
    }

    // ---- symlog of sorted values (monotone => symlog(sort) == sort(symlog)) ----
    #pragma unroll
    for (int e = 0; e < 8; e++) v[e] = symlogf_(v[e]);

    // ---- publish sorted symlog values for neighbor access ----
    __syncthreads();
    #pragma unroll
    for (int e = 0; e < 8; e++) vals[b + e] = v[e];
    __syncthreads();

    // vv[m] = sorted value at position b-2+m (0 outside range)
    float vv[12];
    vv[0]  = (b - 2 >= 0) ? vals[b - 2] : 0.0f;
    vv[1]  = (b - 1 >= 0) ? vals[b - 1] : 0.0f;
    #pragma unroll
    for (int e = 0; e < 8; e++) vv[2 + e] = v[e];
    vv[10] = (b + 8 < NN) ? vals[b + 8] : 0.0f;
    vv[11] = (b + 9 < NN) ? vals[b + 9] : 0.0f;

    // ---- conv1 columns for positions b-1 .. b+8 (10 cols x 8 ch), registers ----
    // weights read from global with uniform indices -> scalar loads (SGPR)
    float h1c[10][8];
    #pragma unroll
    for (int m = 0; m < 10; m++) {
        const int q = b - 1 + m;
        const bool ok = (q >= 0) && (q < NN);
        const float xm = vv[m], xc = vv[m + 1], xp = vv[m + 2];
        #pragma unroll
        for (int c = 0; c < 8; c++) {
            float a = c1b[c];
            a = fmaf(c1w[c * 3 + 0], xm, a);
            a = fmaf(c1w[c * 3 + 1], xc, a);
            a = fmaf(c1w[c * 3 + 2], xp, a);
            h1c[m][c] = ok ? fmaxf(a, 0.0f) : 0.0f;
        }
    }

    // ---- conv2 + relu + per-thread partial mean-pool ----
    float sums[16];
    #pragma unroll
    for (int ch = 0; ch < 16; ch++) {
        const float bb = c2b[ch];
        float acc = 0.0f;
        #pragma unroll
        for (int i = 0; i < 8; i++) {
            float a = bb;
            #pragma unroll
            for (int c = 0; c < 8; c++) {
                a = fmaf(c2w[ch * 24 + c * 3 + 0], h1c[i][c],     a);
                a = fmaf(c2w[ch * 24 + c * 3 + 1], h1c[i + 1][c], a);
                a = fmaf(c2w[ch * 24 + c * 3 + 2], h1c[i + 2][c], a);
            }
            acc += fmaxf(a, 0.0f);
        }
        sums[ch] = acc;
    }

    // ---- block reduction of 16 channel sums ----
    const int wave = t >> 6, lane = t & 63;
    #pragma unroll
    for (int c = 0; c < 16; c++)
        for (int o = 32; o; o >>= 1) sums[c] += __shfl_down(sums[c], o);
    if (lane == 0)
        #pragma unroll
        for (int c = 0; c < 16; c++) red[wave * 16 + c] = sums[c];
    __syncthreads();
    if (t < 16)
        pooled[t] = (red[t] + red[16 + t] + red[32 + t] + red[48 + t]) * (1.0f / NN);
    __syncthreads();
    if (t < OHF) {
        float a = fcb[t];
        #pragma unroll
        for (int c = 0; c < 16; c++) a = fmaf(fcw[t * 16 + c], pooled[c], a);
        ohfeat[r * OHF + t] = a;
    }
}

// ---------------------------------------------------------------------------
// K2: xh = concat([x, oh_feat]) @ lin_w.T   -> [N, 512]
//     4 nodes per block so lin_w L2 traffic is amortized 4x.
// ---------------------------------------------------------------------------
__global__ __launch_bounds__(256) void k_xh(
    const float* __restrict__ x, const float* __restrict__ ohf,
    const float* __restrict__ lin_w, float* __restrict__ xh) {
    const int n0 = blockIdx.x * 4;
    __shared__ float xin[4][136];
    const int tid = threadIdx.x;
    for (int i = tid; i < 4 * 136; i += 256) {
        int nn = i / 136, k = i - nn * 136;
        xin[nn][k] = (k < INF_) ? x[(size_t)(n0+nn)*INF_ + k]
                                : ohf[(n0+nn)*OHF + (k - INF_)];
    }
    __syncthreads();
    for (int o = tid; o < 512; o += 256) {
        const float4* wr4 = (const float4*)(lin_w + (size_t)o * 136);
        float a0 = 0, a1 = 0, a2 = 0, a3 = 0;
        for (int kk = 0; kk < 34; kk++) {
            float4 w = wr4[kk];
            int k = kk * 4;
            a0 += w.x*xin[0][k] + w.y*xin[0][k+1] + w.z*xin[0][k+2] + w.w*xin[0][k+3];
            a1 += w.x*xin[1][k] + w.y*xin[1][k+1] + w.z*xin[1][k+2] + w.w*xin[1][k+3];
            a2 += w.x*xin[2][k] + w.y*xin[2][k+1] + w.z*xin[2][k+2] + w.w*xin[2][k+3];
            a3 += w.x*xin[3][k] + w.y*xin[3][k+1] + w.z*xin[3][k+2] + w.w*xin[3][k+3];
        }
        xh[(size_t)(n0+0)*512 + o] = a0;
        xh[(size_t)(n0+1)*512 + o] = a1;
        xh[(size_t)(n0+2)*512 + o] = a2;
        xh[(size_t)(n0+3)*512 + o] = a3;
    }
}

// ---------------------------------------------------------------------------
// K3: sa/ra attention logits per (node, head). 4 waves/block, 1 node/block.
// ---------------------------------------------------------------------------
__global__ __launch_bounds__(256) void k_attn(
    const float* __restrict__ xh, const float* __restrict__ att_l,
    const float* __restrict__ att_r, float* __restrict__ sa,
    float* __restrict__ ra) {
    const int n = blockIdx.x;
    const int tid = threadIdx.x, wave = tid >> 6, lane = tid & 63;
    const float* xr = xh + (size_t)n * 512 + wave * 128;
    float v0 = xr[lane], v1 = xr[lane + 64];
    float pl = v0 * att_l[wave*128 + lane] + v1 * att_l[wave*128 + lane + 64];
    float pr = v0 * att_r[wave*128 + lane] + v1 * att_r[wave*128 + lane + 64];
    for (int o = 32; o; o >>= 1) { pl += __shfl_down(pl, o); pr += __shfl_down(pr, o); }
    if (lane == 0) { sa[n*4 + wave] = pl; ra[n*4 + wave] = pr; }
}

// ---------------------------------------------------------------------------
// CSR build by destination (counting sort).
// ---------------------------------------------------------------------------
__global__ void k_count(const int* __restrict__ dst, int* __restrict__ deg) {
    int e = blockIdx.x * 256 + threadIdx.x;
    if (e < NET) {
        int d = (e < NE) ? dst[e] : (e - NE);
        atomicAdd(&deg[d], 1);
    }
}

__global__ __launch_bounds__(256) void k_scan(
    const int* __restrict__ deg, int* __restrict__ csr_off,
    int* __restrict__ csr_pos) {
    __shared__ int tot[256];
    __shared__ int base[257];
    const int t = threadIdx.x;
    int loc[8], s = 0;
    for (int k = 0; k < 8; k++) { loc[k] = deg[t*8 + k]; s += loc[k]; }
    tot[t] = s;
    __syncthreads();
    if (t == 0) {
        int acc = 0;
        for (int i = 0; i < 256; i++) { base[i] = acc; acc += tot[i]; }
        base[256] = acc;
    }
    __syncthreads();
    int b = base[t];
    for (int k = 0; k < 8; k++) {
        csr_off[t*8 + k] = b;
        csr_pos[t*8 + k] = b;
        b += loc[k];
    }
    if (t == 0) csr_off[NN] = base[256];
}

__global__ void k_fill(const int* __restrict__ dst, int* __restrict__ csr_pos,
                       int* __restrict__ csr_e) {
    int e = blockIdx.x * 256 + threadIdx.x;
    if (e < NET) {
        int d = (e < NE) ? dst[e] : (e - NE);
        int pos = atomicAdd(&csr_pos[d], 1);
        csr_e[pos] = e;
    }
}

// ---------------------------------------------------------------------------
// K4: per-edge raw attention: leaky_relu(sa[s]+ra[d]) / (slog[s].slog[d] + 1)
// ---------------------------------------------------------------------------
__global__ __launch_bounds__(256) void k_alpha(
    const int* __restrict__ src, const int* __restrict__ dst,
    const float* __restrict__ slog, const float* __restrict__ sa,
    const float* __restrict__ ra, float* __restrict__ alpha) {
    const int e = blockIdx.x;
    int s, d;
    if (e < NE) { s = src[e]; d = dst[e]; } else { s = d = e - NE; }
    const int tid = threadIdx.x;
    const float4* A = (const float4*)(slog + (size_t)s * NN);
    const float4* B = (const float4*)(slog + (size_t)d * NN);
    float4 a0 = A[tid*2], a1 = A[tid*2 + 1];
    float4 b0 = B[tid*2], b1 = B[tid*2 + 1];
    float p = a0.x*b0.x + a0.y*b0.y + a0.z*b0.z + a0.w*b0.w
            + a1.x*b1.x + a1.y*b1.y + a1.z*b1.z + a1.w*b1.w;
    for (int o = 32; o; o >>= 1) p += __shfl_down(p, o);
    __shared__ float ps[4];
    const int wave = tid >> 6, lane = tid & 63;
    if (lane == 0) ps[wave] = p;
    __syncthreads();
    if (tid == 0) {
        float dot  = ps[0] + ps[1] + ps[2] + ps[3];
        float datt = 1.0f / (dot + 1.0f);
        float4 out;
        float* po = (float*)&out;
        for (int h = 0; h < 4; h++) {
            float a = sa[s*4 + h] + ra[d*4 + h];
            a = (a >= 0.0f) ? a : NEG_SLOPE * a;
            po[h] = a * datt;
        }
        *(float4*)(alpha + (size_t)e * 4) = out;
    }
}

// ---------------------------------------------------------------------------
// K5: per destination node: segment softmax over incoming edges + weighted
//     aggregation of xh[s] rows. new_x = agg + bias.
// ---------------------------------------------------------------------------
__global__ __launch_bounds__(256) void k_soft_aggx(
    const int* __restrict__ src, const int* __restrict__ csr_off,
    const int* __restrict__ csr_e, const float* __restrict__ alpha,
    const float* __restrict__ xh, const float* __restrict__ bias,
    float* __restrict__ out_x) {
    const int d = blockIdx.x;
    const int begin = csr_off[d];
    int deg = csr_off[d + 1] - begin;
    if (deg > CAP) deg = CAP;   // unreachable for this input distribution
    __shared__ float wls[CAP * 4];
    __shared__ int   sls[CAP];
    const int tid = threadIdx.x;
    for (int t = tid; t < deg; t += 256) {
        int e = csr_e[begin + t];
        sls[t] = (e < NE) ? src[e] : (e - NE);
        float4 a = *(const float4*)(alpha + (size_t)e * 4);
        wls[t*4 + 0] = a.x; wls[t*4 + 1] = a.y;
        wls[t*4 + 2] = a.z; wls[t*4 + 3] = a.w;
    }
    __syncthreads();
    const int wave = tid >> 6, lane = tid & 63;
    if (wave < 4) {  // wave w owns head w
        float m = -3.4e38f;
        for (int t = lane; t < deg; t += 64) m = fmaxf(m, wls[t*4 + wave]);
        for (int o = 32; o; o >>= 1) m = fmaxf(m, __shfl_down(m, o));
        m = __shfl(m, 0);
        float s = 0.0f;
        for (int t = lane; t < deg; t += 64) {
            float ex = expf(wls[t*4 + wave] - m);
            wls[t*4 + wave] = ex;
            s += ex;
        }
        for (int o = 32; o; o >>= 1) s += __shfl_down(s, o);
        s = __shfl(s, 0);
        float inv = 1.0f / (s + 1e-16f);
        for (int t = lane; t < deg; t += 64) wls[t*4 + wave] *= inv;
    }
    __syncthreads();
    for (int ho = tid; ho < 512; ho += 256) {
        const int h = ho >> 7;
        float acc = 0.0f;
        for (int t = 0; t < deg; t++)
            acc += wls[t*4 + h] * xh[(size_t)sls[t] * 512 + ho];
        out_x[(size_t)d * 512 + ho] = acc + bias[ho];
    }
}

// ---------------------------------------------------------------------------
// K6: new_onehot = onehot + sum over incoming edges of onehot[s].
// ---------------------------------------------------------------------------
__global__ __launch_bounds__(256) void k_aggoh(
    const float* __restrict__ onehot, const int* __restrict__ src,
    const int* __restrict__ csr_off, const int* __restrict__ csr_e,
    float* __restrict__ out_oh) {
    const int d = blockIdx.x;
    const int begin = csr_off[d], end = csr_off[d + 1];
    const int tid = threadIdx.x;
    const float4* own = (const float4*)(onehot + (size_t)d * NN);
    float4 A = own[tid], B = own[tid + 256];
    for (int p = begin; p < end; p++) {
        int e = csr_e[p];
        int s = (e < NE) ? src[e] : (e - NE);
        const float4* r4 = (const float4*)(onehot + (size_t)s * NN);
        float4 u = r4[tid], v = r4[tid + 256];
        A.x += u.x; A.y += u.y; A.z += u.z; A.w += u.w;
        B.x += v.x; B.y += v.y; B.z += v.z; B.w += v.w;
    }
    float4* o4 = (float4*)(out_oh + (size_t)d * NN);
    o4[tid] = A; o4[tid + 256] = B;
}

// ---------------------------------------------------------------------------
extern "C" void kernel_launch(void* const* d_in, const int* in_sizes, int n_in,
                              void* d_out, int out_size, void* d_ws, size_t ws_size,
                              hipStream_t stream) {
    const float* x      = (const float*)d_in[0];
    const float* onehot = (const float*)d_in[1];
    const int*   src    = (const int*)d_in[2];
    const int*   dst    = (const int*)d_in[3];
    const float* lin_w  = (const float*)d_in[4];
    const float* att_l  = (const float*)d_in[5];
    const float* att_r  = (const float*)d_in[6];
    const float* bias   = (const float*)d_in[7];
    const float* c1w    = (const float*)d_in[8];
    const float* c1b    = (const float*)d_in[9];
    const float* c2w    = (const float*)d_in[10];
    const float* c2b    = (const float*)d_in[11];
    const float* fcw    = (const float*)d_in[12];
    const float* fcb    = (const float*)d_in[13];

    float* out_x  = (float*)d_out;                       // [N, 512]
    float* out_oh = out_x + (size_t)NN * (NH * OUTF);    // [N, N]

    // Workspace layout (~21.5 MB)
    float* ws    = (float*)d_ws;
    float* slog  = ws;                           // N*N
    float* xh    = slog + (size_t)NN * NN;       // N*512
    float* ohf   = xh   + (size_t)NN * 512;      // N*8
    float* sa    = ohf  + (size_t)NN * OHF;      // N*4
    float* ra    = sa   + (size_t)NN * NH;       // N*4
    float* alpha = ra   + (size_t)NN * NH;       // NET*4
    int* deg     = (int*)(alpha + (size_t)NET * 4);
    int* csr_off = deg + NN;                     // N+1
    int* csr_pos = csr_off + NN + 1;             // N
    int* csr_e   = csr_pos + NN;                 // NET

    hipMemsetAsync(deg, 0, NN * sizeof(int), stream);
    k_sortconv<<<NN, 256, 0, stream>>>(onehot, c1w, c1b, c2w, c2b, fcw, fcb, slog, ohf);
    k_count<<<(NET + 255) / 256, 256, 0, stream>>>(dst, deg);
    k_scan<<<1, 256, 0, stream>>>(deg, csr_off, csr_pos);
    k_fill<<<(NET + 255) / 256, 256, 0, stream>>>(dst, csr_pos, csr_e);
    k_xh<<<NN / 4, 256, 0, stream>>>(x, ohf, lin_w, xh);
    k_attn<<<NN, 256, 0, stream>>>(xh, att_l, att_r, sa, ra);
    k_alpha<<<NET, 256, 0, stream>>>(src, dst, slog, sa, ra, alpha);
    k_soft_aggx<<<NN, 256, 0, stream>>>(src, csr_off, csr_e, alpha, xh, bias, out_x);
    k_aggoh<<<NN, 256, 0, stream>>>(onehot, src, csr_off, csr_e, out_oh);
}